// Round 12
// baseline (2830.041 us; speedup 1.0000x reference)
//
#include <hip/hip_runtime.h>

// LSTM_88776974008866: bidirectional LSTM (B=2048, S=128, H=512, in=4) + 4 sigmoid heads.
// Round 12: DUAL-STREAM blocks. Each block owns 256 batch rows x 64 perm cols of BOTH
// directions; the K-loop interleaves fwd/bwd slices -- two independent dependency
// chains per wave so L2 load latency of one hides under MFMAs of the other (r11's
// residual was a single latency-diluted chain). W = 2 x 68KB LDS images (136KB -> still
// 1 block/CU; r9 lesson: never share L1 across protocol blocks). Intra-block duplicate
// A-loads eliminated (waves own disjoint 32-row sets per dir).
// Protocol verbatim from r8/r11 (validated): XCD-exact groups via HW_REG_XCC_ID + rank,
// single-writer RELAXED flags (agent acquire=invl2 / release-store=wbl2 are measured
// disasters), parallel poll (one RMW instruction for all 32 flags), publish after
// vmcnt(0) drain + LDS arrival, per-step L1-only `buffer_inv sc0`.
// x*Wih+bias folded as K-slice 16 of each LDS image; tail MFMA after the main loop
// (caps peak VGPR ~230; r10 lesson: spills => GB-scale FETCH/WRITE => abort signature).

typedef __attribute__((ext_vector_type(8))) __bf16 bf16x8;
typedef __attribute__((ext_vector_type(4))) float f32x4;
typedef __attribute__((ext_vector_type(8))) unsigned short u16x8;

__device__ __forceinline__ unsigned short f2bf(float f) {
  unsigned u = __float_as_uint(f);
  u += 0x7fffu + ((u >> 16) & 1u);   // round-to-nearest-even
  return (unsigned short)(u >> 16);
}
__device__ __forceinline__ float bf2f(unsigned short s) {
  return __uint_as_float(((unsigned)s) << 16);
}
__device__ __forceinline__ float sigm(float x) { return 1.0f / (1.0f + __expf(-x)); }
__device__ __forceinline__ float tanhfast(float x) {
  float e = __expf(-2.0f * fabsf(x));
  float t = (1.0f - e) / (1.0f + e);
  return x < 0.0f ? -t : t;
}

__device__ __forceinline__ void gl_lds16(const void* g, void* l) {
  __builtin_amdgcn_global_load_lds(
      (const __attribute__((address_space(1))) unsigned int*)g,
      (__attribute__((address_space(3))) unsigned int*)l, 16, 0, 0);
}

// ---------------------------------------------------------------------------
// prep: Whh (fp32 [2048][512], gate-major i,f,g,o) -> per-(dir,band) 68KB images,
// 17 K-slices (16 real + tail). 16B chunk:
//   flat = (((dir*32+band)*17 + kt)*4 + nf)*64 + lane
//   lane: l15 -> col j = band*16+l15 (gate=nf, orig = nf*512+j); lhi -> k-quad.
//   kt<16: Whh[orig][kt*32+lhi*8 .. +8]; kt==16 & lhi==0: {wih[orig][0..3], bias,0,0,0}.
// ---------------------------------------------------------------------------
__global__ __launch_bounds__(256) void prep_k(
    const float* __restrict__ Wf_hh, const float* __restrict__ Wf_ih,
    const float* __restrict__ bf_ih, const float* __restrict__ bf_hh,
    const float* __restrict__ Wb_hh, const float* __restrict__ Wb_ih,
    const float* __restrict__ bb_ih, const float* __restrict__ bb_hh,
    unsigned short* __restrict__ Wimg)
{
  int flat = blockIdx.x * 256 + threadIdx.x;   // 0 .. 278527
  int lane = flat & 63;
  int nf = (flat >> 6) & 3;
  int q = flat >> 8;                           // (dir*32+band)*17 + kt
  int kt = q % 17;
  int dn = q / 17;                             // 0..63
  int band = dn & 31;
  int dir = dn >> 5;
  int l15 = lane & 15, lhi = lane >> 4;
  const float* Whh = dir ? Wb_hh : Wf_hh;
  const float* Wih = dir ? Wb_ih : Wf_ih;
  const float* bih = dir ? bb_ih : bf_ih;
  const float* bhh = dir ? bb_hh : bf_hh;

  int j = (band << 4) + l15;                   // hidden index 0..511
  int orig = (nf << 9) + j;                    // gate-major row in [0,2048)

  u16x8 o = {};
  if (kt < 16) {
    int k0 = (kt << 5) + (lhi << 3);
    const float4* src = (const float4*)(Whh + (size_t)orig * 512 + k0);
    float4 a = src[0], b = src[1];
    o[0] = f2bf(a.x); o[1] = f2bf(a.y); o[2] = f2bf(a.z); o[3] = f2bf(a.w);
    o[4] = f2bf(b.x); o[5] = f2bf(b.y); o[6] = f2bf(b.z); o[7] = f2bf(b.w);
  } else if (lhi == 0) {
    o[0] = f2bf(Wih[orig * 4 + 0]);
    o[1] = f2bf(Wih[orig * 4 + 1]);
    o[2] = f2bf(Wih[orig * 4 + 2]);
    o[3] = f2bf(Wih[orig * 4 + 3]);
    o[4] = f2bf(bih[orig] + bhh[orig]);
  }
  *(u16x8*)(Wimg + (size_t)flat * 8) = o;
}

__device__ __forceinline__ void mfma8(const bf16x8 av[2], const bf16x8 bv[4],
                                      f32x4 acc[2][4]) {
#pragma unroll
  for (int mf = 0; mf < 2; ++mf)
#pragma unroll
    for (int nf = 0; nf < 4; ++nf)
      acc[mf][nf] = __builtin_amdgcn_mfma_f32_16x16x32_bf16(av[mf], bv[nf], acc[mf][nf], 0, 0, 0);
}

// ---------------------------------------------------------------------------
// Persistent kernel: 256 blocks x 512 threads (1 block/CU via 136KB LDS),
// cooperative launch => exactly 32 blocks per XCD. Roles: xcc = HW_REG_XCC_ID,
// rank = per-XCD counter 0..31 = column band (j in [rank*16, +16), both dirs).
// All 32 blocks of an XCD form ONE group producing/consuming both h panels
// (rows xcc*256..+256) in their shared physical L2.
// Wave w: rows [w*32,+32); per dir: A-frags mf in {0,1}, B = 64 cols (4 nf).
// ctrl (uints): [xcc<<5] rank counters; flags at 256 + xcc*1024 + rank*32.
// ---------------------------------------------------------------------------
__global__ __launch_bounds__(512, 2) void lstm_persist(
    const float* __restrict__ y,
    const unsigned short* __restrict__ Wp,
    unsigned short* __restrict__ hf0, unsigned short* __restrict__ hf1,
    unsigned short* __restrict__ hb0, unsigned short* __restrict__ hb1,
    unsigned* __restrict__ ctrl)
{
  __shared__ alignas(16) unsigned short Wl[69632];   // 136KB: fwd 68KB | bwd 68KB
  __shared__ unsigned arrive_cnt;
  __shared__ unsigned rank_sh;

  const int tid = threadIdx.x;
  const int w = tid >> 6, lane = tid & 63;
  const int l15 = lane & 15, lhi = lane >> 4;

  unsigned xcc;
  asm("s_getreg_b32 %0, hwreg(HW_REG_XCC_ID)" : "=s"(xcc));
  xcc &= 7u;

  if (tid == 0) {
    arrive_cnt = 0u;
    rank_sh = __hip_atomic_fetch_add(ctrl + (xcc << 5), 1u,
                                     __ATOMIC_RELAXED, __HIP_MEMORY_SCOPE_AGENT);
  }
  __syncthreads();
  const int rank = (int)(rank_sh & 31u);   // column band, both dirs
  const int bm0 = (int)xcc << 8;           // this XCD's 256 batch rows
  const int j0 = rank << 4;

  // ---- one-time: stage both 68KB W images into LDS (17 x 8KB rounds) ----
  // image chunks: fwd = Wp[(rank)*4352 ...], bwd = Wp[(32+rank)*4352 ...]
  for (int i = 0; i < 17; ++i) {
    int c0 = (i << 9) + (w << 6);          // wave-uniform chunk base (4352 % 64 == 0)
    const unsigned short* src =
        (c0 < 4352) ? Wp + ((size_t)rank * 4352 + c0 + lane) * 8
                    : Wp + ((size_t)(32 + rank) * 4352 + (c0 - 4352) + lane) * 8;
    gl_lds16(src, (unsigned short*)Wl + (size_t)c0 * 8);
  }

  float c_reg[16];                          // [dir*8 + mf*4 + r]
#pragma unroll
  for (int i = 0; i < 16; ++i) c_reg[i] = 0.f;

  const float4* y4 = (const float4*)y;
  unsigned* flags  = ctrl + 256 + ((unsigned)xcc << 10);   // 32 flags, 128B apart
  unsigned* myflag = flags + ((unsigned)rank << 5);        // single writer

  const unsigned short* wBf = Wl + (lane << 3);            // fwd image base
  const unsigned short* wBb = Wl + 34816 + (lane << 3);    // bwd image base

  __syncthreads();   // Wl ready (drains global_load_lds)

#pragma unroll 1
  for (int t = 0; t < 128; ++t) {
    const unsigned short* hf_in = (t & 1) ? hf1 : hf0;
    unsigned short* hf_out      = (t & 1) ? hf0 : hf1;
    const unsigned short* hb_in = (t & 1) ? hb1 : hb0;
    unsigned short* hb_out      = (t & 1) ? hb0 : hb1;

    // ---- x -> register tail-A fragments for both dirs (independent of flags) ----
    bf16x8 atf[2], atb[2];
#pragma unroll
    for (int mf = 0; mf < 2; ++mf) {
      const size_t row = (size_t)(bm0 + (w << 5) + (mf << 4) + l15) * 128;
      float4 xf = y4[row + t];
      float4 xb = y4[row + (127 - t)];
      u16x8 af = {}, ab = {};
      if (lhi == 0) {
        af[0] = f2bf(xf.x); af[1] = f2bf(xf.y); af[2] = f2bf(xf.z); af[3] = f2bf(xf.w);
        af[4] = 0x3F80;
        ab[0] = f2bf(xb.x); ab[1] = f2bf(xb.y); ab[2] = f2bf(xb.z); ab[3] = f2bf(xb.w);
        ab[4] = 0x3F80;
      }
      atf[mf] = *(bf16x8*)&af;
      atb[mf] = *(bf16x8*)&ab;
    }

    // ---- wait for all 32 XCD peers (parallel relaxed RMW poll), L1-only inv ----
    if (t) {
      if (w == 0) {
        unsigned* fp = flags + ((lane & 31) << 5);
        while (true) {
          unsigned v = 0;
          if (lane < 32)
            v = __hip_atomic_fetch_add(fp, 0u, __ATOMIC_RELAXED,
                                       __HIP_MEMORY_SCOPE_AGENT);
          bool ok = (lane < 32) ? (v >= (unsigned)t) : true;
          if (__all(ok)) break;
          __builtin_amdgcn_s_sleep(2);
        }
      }
      __syncthreads();
      asm volatile("buffer_inv sc0\n\ts_waitcnt vmcnt(0)" ::: "memory");
    }

    f32x4 accF[2][4], accB[2][4];
#pragma unroll
    for (int a = 0; a < 2; ++a)
#pragma unroll
      for (int b = 0; b < 4; ++b) {
        accF[a][b] = (f32x4){0.f, 0.f, 0.f, 0.f};
        accB[a][b] = (f32x4){0.f, 0.f, 0.f, 0.f};
      }

    if (t) {
      const size_t arow = ((size_t)(bm0 + (w << 5) + l15) << 9) + (lhi << 3);
      const unsigned short* aFb = hf_in + arow;
      const unsigned short* aBb_ = hb_in + arow;

      bf16x8 aF[3][2], aB[3][2], bF[2][4], bB[2][4];

#define SL(i) ((rank + (i)) & 15)
#define ALOADF(kk, sl)                                                         \
      do { const unsigned short* p_ = aFb + ((kk) << 5);                       \
        aF[sl][0] = *(const bf16x8*)(p_);                                      \
        aF[sl][1] = *(const bf16x8*)(p_ + (16 << 9)); } while (0)
#define ALOADB(kk, sl)                                                         \
      do { const unsigned short* p_ = aBb_ + ((kk) << 5);                      \
        aB[sl][0] = *(const bf16x8*)(p_);                                      \
        aB[sl][1] = *(const bf16x8*)(p_ + (16 << 9)); } while (0)
#define BLOADF(kk, sl)                                                         \
      do { const unsigned short* p_ = wBf + ((kk) << 11);                      \
        bF[sl][0] = *(const bf16x8*)(p_);                                      \
        bF[sl][1] = *(const bf16x8*)(p_ + 512);                                \
        bF[sl][2] = *(const bf16x8*)(p_ + 1024);                               \
        bF[sl][3] = *(const bf16x8*)(p_ + 1536); } while (0)
#define BLOADB(kk, sl)                                                         \
      do { const unsigned short* p_ = wBb + ((kk) << 11);                      \
        bB[sl][0] = *(const bf16x8*)(p_);                                      \
        bB[sl][1] = *(const bf16x8*)(p_ + 512);                                \
        bB[sl][2] = *(const bf16x8*)(p_ + 1024);                               \
        bB[sl][3] = *(const bf16x8*)(p_ + 1536); } while (0)

      ALOADF(SL(0), 0); ALOADB(SL(0), 0);
      ALOADF(SL(1), 1); ALOADB(SL(1), 1);
      ALOADF(SL(2), 2); ALOADB(SL(2), 2);
      BLOADF(SL(0), 0); BLOADB(SL(0), 0);
      BLOADF(SL(1), 1); BLOADB(SL(1), 1);

#pragma unroll
      for (int i = 0; i < 16; ++i) {
        __builtin_amdgcn_s_setprio(1);
        mfma8(aF[i % 3], bF[i & 1], accF);
        __builtin_amdgcn_s_setprio(0);
        if (i < 13) ALOADF(SL(i + 3), (i + 3) % 3);
        if (i < 14) BLOADF(SL(i + 2), i & 1);
        __builtin_amdgcn_s_setprio(1);
        mfma8(aB[i % 3], bB[i & 1], accB);
        __builtin_amdgcn_s_setprio(0);
        if (i < 13) ALOADB(SL(i + 3), (i + 3) % 3);
        if (i < 14) BLOADB(SL(i + 2), i & 1);
      }
#undef ALOADF
#undef ALOADB
#undef BLOADF
#undef BLOADB
#undef SL
    }

    // ---- tail MFMA (x*Wih + bias, slice 16 of each LDS image) ----
    {
      bf16x8 btf[4], btb[4];
#pragma unroll
      for (int nf = 0; nf < 4; ++nf) {
        btf[nf] = *(const bf16x8*)(wBf + (16 << 11) + (nf << 9));
        btb[nf] = *(const bf16x8*)(wBb + (16 << 11) + (nf << 9));
      }
      mfma8(atf, btf, accF);
      mfma8(atb, btb, accB);
    }

    // ---- epilogues: lane-local cell updates, c in registers ----
#pragma unroll
    for (int mf = 0; mf < 2; ++mf) {
#pragma unroll
      for (int r = 0; r < 4; ++r) {
        const int b = bm0 + (w << 5) + (mf << 4) + (lhi << 2) + r;
        // fwd
        {
          const float ig = sigm(accF[mf][0][r]);
          const float fg = sigm(accF[mf][1][r]);
          const float gg = tanhfast(accF[mf][2][r]);
          const float og = sigm(accF[mf][3][r]);
          const float cn = fg * c_reg[(mf << 2) + r] + ig * gg;
          c_reg[(mf << 2) + r] = cn;
          hf_out[((size_t)b << 9) + j0 + l15] = f2bf(og * tanhfast(cn));
        }
        // bwd
        {
          const float ig = sigm(accB[mf][0][r]);
          const float fg = sigm(accB[mf][1][r]);
          const float gg = tanhfast(accB[mf][2][r]);
          const float og = sigm(accB[mf][3][r]);
          const float cn = fg * c_reg[8 + (mf << 2) + r] + ig * gg;
          c_reg[8 + (mf << 2) + r] = cn;
          hb_out[((size_t)b << 9) + j0 + l15] = f2bf(og * tanhfast(cn));
        }
      }
    }

    // ---- publish: per-wave store drain -> LDS arrival -> 8th wave bumps OWN flag ----
    if (t != 127) {
      asm volatile("s_waitcnt vmcnt(0)" ::: "memory");   // own h stores in L2
      if (lane == 0) {
        unsigned old = atomicAdd(&arrive_cnt, 1u);       // intra-block LDS atomic
        if (old == (unsigned)((t << 3) + 7)) {           // last of 8 waves this step
          __hip_atomic_fetch_add(myflag, 1u, __ATOMIC_RELAXED,
                                 __HIP_MEMORY_SCOPE_AGENT);
        }
      }
    }
  }
}

// ---------------------------------------------------------------------------
// heads: out[b][k] = sigmoid(hf[b]·Wk[0:512] + hb[b]·Wk[512:1024] + bk)
// ---------------------------------------------------------------------------
__global__ __launch_bounds__(256) void heads_k(
    const unsigned short* __restrict__ hf, const unsigned short* __restrict__ hb,
    const float* __restrict__ W1, const float* __restrict__ b1,
    const float* __restrict__ W2, const float* __restrict__ b2,
    const float* __restrict__ W3, const float* __restrict__ b3,
    const float* __restrict__ W4, const float* __restrict__ b4,
    float* __restrict__ out)
{
  const int wid = threadIdx.x >> 6, lane = threadIdx.x & 63;
  const int b = blockIdx.x * 4 + wid;
  const unsigned short* src = (lane < 32) ? (hf + ((size_t)b << 9) + (lane << 4))
                                          : (hb + ((size_t)b << 9) + ((lane - 32) << 4));
  const int woff = lane << 4;
  u16x8 v0 = *(const u16x8*)src;
  u16x8 v1 = *(const u16x8*)(src + 8);
  float hv[16];
#pragma unroll
  for (int e = 0; e < 8; ++e) { hv[e] = bf2f(v0[e]); hv[8 + e] = bf2f(v1[e]); }
  float s0 = 0.f, s1 = 0.f, s2 = 0.f, s3 = 0.f;
#pragma unroll
  for (int e = 0; e < 16; ++e) {
    float h = hv[e];
    s0 += h * W1[woff + e];
    s1 += h * W2[woff + e];
    s2 += h * W3[woff + e];
    s3 += h * W4[woff + e];
  }
#pragma unroll
  for (int off = 32; off >= 1; off >>= 1) {
    s0 += __shfl_xor(s0, off, 64);
    s1 += __shfl_xor(s1, off, 64);
    s2 += __shfl_xor(s2, off, 64);
    s3 += __shfl_xor(s3, off, 64);
  }
  if (lane == 0) {
    out[b * 4 + 0] = sigm(s0 + b1[0]);
    out[b * 4 + 1] = sigm(s1 + b2[0]);
    out[b * 4 + 2] = sigm(s2 + b3[0]);
    out[b * 4 + 3] = sigm(s3 + b4[0]);
  }
}

// ---------------------------------------------------------------------------
extern "C" void kernel_launch(void* const* d_in, const int* in_sizes, int n_in,
                              void* d_out, int out_size, void* d_ws, size_t ws_size,
                              hipStream_t stream) {
  (void)in_sizes; (void)n_in; (void)out_size; (void)ws_size;
  const float* y     = (const float*)d_in[0];
  const float* Wf_ih = (const float*)d_in[1];
  const float* Wf_hh = (const float*)d_in[2];
  const float* bf_ih = (const float*)d_in[3];
  const float* bf_hh = (const float*)d_in[4];
  const float* Wb_ih = (const float*)d_in[5];
  const float* Wb_hh = (const float*)d_in[6];
  const float* bb_ih = (const float*)d_in[7];
  const float* bb_hh = (const float*)d_in[8];
  const float* W1 = (const float*)d_in[9];  const float* b1 = (const float*)d_in[10];
  const float* W2 = (const float*)d_in[11]; const float* b2 = (const float*)d_in[12];
  const float* W3 = (const float*)d_in[13]; const float* b3 = (const float*)d_in[14];
  const float* W4 = (const float*)d_in[15]; const float* b4 = (const float*)d_in[16];

  char* ws = (char*)d_ws;
  const size_t MB = 1ull << 20;
  unsigned short* Wp  = (unsigned short*)(ws);            // 4.25MB: 64 x 68KB images
  unsigned short* hf0 = (unsigned short*)(ws + 5 * MB);   // 2MB
  unsigned short* hb0 = (unsigned short*)(ws + 7 * MB);   // 2MB
  unsigned short* hf1 = (unsigned short*)(ws + 9 * MB);   // 2MB
  unsigned short* hb1 = (unsigned short*)(ws + 11 * MB);  // 2MB
  unsigned* ctrl      = (unsigned*)(ws + 13 * MB);        // rank counters + flags

  hipMemsetAsync(ws + 5 * MB, 0, 4 * MB, stream);    // hf0+hb0 = h(t=0) zeros
  hipMemsetAsync(ws + 13 * MB, 0, 65536, stream);    // ctrl: counters + flags

  prep_k<<<1088, 256, 0, stream>>>(Wf_hh, Wf_ih, bf_ih, bf_hh,
                                   Wb_hh, Wb_ih, bb_ih, bb_hh, Wp);

  void* args[] = { (void*)&y, (void*)&Wp,
                   (void*)&hf0, (void*)&hf1, (void*)&hb0, (void*)&hb1, (void*)&ctrl };
  hipLaunchCooperativeKernel((const void*)lstm_persist, dim3(256), dim3(512),
                             args, 0, stream);

  // 128 steps (even): final h is in buffer 0 for both directions
  heads_k<<<512, 256, 0, stream>>>(hf0, hb0, W1, b1, W2, b2, W3, b3, W4, b4,
                                   (float*)d_out);
}

// Round 13
// 2454.264 us; speedup vs baseline: 1.1531x; 1.1531x over previous
//
#include <hip/hip_runtime.h>

// LSTM_88776974008866: bidirectional LSTM (B=2048, S=128, H=512, in=4) + 4 sigmoid heads.
// Round 13: r11 verbatim with ONE change -- the poll uses relaxed agent LOADS instead of
// fetch_add(0) RMWs. RMW polls lock the flag line at the LLC: 15 pollers' RMWs queue
// ahead of the straggler's publish RMW (line saturated => every step's start serialized).
// Loads don't lock lines (concurrent readers OK) and are fresh (device-scope bypass
// bits; r5/r6 load-spins validated no livelock). Publish stays single-writer relaxed RMW.
// Ledger (validated across r3-r12): agent acquire = invl2 (25GB refetch), agent release
// store = wbl2 (525MB flush) -- never in the hot loop; h writes must cover full 64B
// lines per block (r12: 32B stripes => 513MB HBM writes); 1 protocol-block per CU only
// (r9: shared L1 + inv unsound); launch_bounds must leave VGPR headroom (r10 spills).

typedef __attribute__((ext_vector_type(8))) __bf16 bf16x8;
typedef __attribute__((ext_vector_type(4))) float f32x4;
typedef __attribute__((ext_vector_type(8))) unsigned short u16x8;

__device__ __forceinline__ unsigned short f2bf(float f) {
  unsigned u = __float_as_uint(f);
  u += 0x7fffu + ((u >> 16) & 1u);   // round-to-nearest-even
  return (unsigned short)(u >> 16);
}
__device__ __forceinline__ float bf2f(unsigned short s) {
  return __uint_as_float(((unsigned)s) << 16);
}
__device__ __forceinline__ float sigm(float x) { return 1.0f / (1.0f + __expf(-x)); }
__device__ __forceinline__ float tanhfast(float x) {
  float e = __expf(-2.0f * fabsf(x));
  float t = (1.0f - e) / (1.0f + e);
  return x < 0.0f ? -t : t;
}

__device__ __forceinline__ void gl_lds16(const void* g, void* l) {
  __builtin_amdgcn_global_load_lds(
      (const __attribute__((address_space(1))) unsigned int*)g,
      (__attribute__((address_space(3))) unsigned int*)l, 16, 0, 0);
}

// ---------------------------------------------------------------------------
// prep (r8 verbatim): Whh (fp32 [2048][512], gate-major i,f,g,o) -> Wp image:
//   chunk = ((((dir*16+ni)*2+wn)*16+kt)*4+nf)*64 + lhi*16 + l15   (16B chunks)
// wtail[dir][permrow][8] = {wih[0..3], bias, 0,0,0} bf16 for the tail MFMA.
// ---------------------------------------------------------------------------
__global__ __launch_bounds__(256) void prep_k(
    const float* __restrict__ Wf_hh, const float* __restrict__ Wf_ih,
    const float* __restrict__ bf_ih, const float* __restrict__ bf_hh,
    const float* __restrict__ Wb_hh, const float* __restrict__ Wb_ih,
    const float* __restrict__ bb_ih, const float* __restrict__ bb_hh,
    unsigned short* __restrict__ Wp, unsigned short* __restrict__ wtailp)
{
  int flat = blockIdx.x * 256 + threadIdx.x;   // 0 .. 262143
  int l15 = flat & 15;
  int lhi = (flat >> 4) & 3;
  int nf  = (flat >> 6) & 3;
  int kt  = (flat >> 8) & 15;
  int wn  = (flat >> 12) & 1;
  int ni  = (flat >> 13) & 15;
  int dir = (flat >> 17) & 1;
  const float* Whh = dir ? Wb_hh : Wf_hh;
  const float* Wih = dir ? Wb_ih : Wf_ih;
  const float* bih = dir ? bb_ih : bf_ih;
  const float* bhh = dir ? bb_hh : bf_hh;

  int j = ((ni * 2 + wn) << 4) + l15;          // hidden index 0..511
  int orig = (nf << 9) + j;                    // original gate-major row
  int k0 = (kt << 5) + (lhi << 3);
  const float4* src = (const float4*)(Whh + (size_t)orig * 512 + k0);
  float4 a = src[0], b = src[1];
  u16x8 o;
  o[0] = f2bf(a.x); o[1] = f2bf(a.y); o[2] = f2bf(a.z); o[3] = f2bf(a.w);
  o[4] = f2bf(b.x); o[5] = f2bf(b.y); o[6] = f2bf(b.z); o[7] = f2bf(b.w);
  *(u16x8*)(Wp + (size_t)flat * 8) = o;

  if (kt == 0 && lhi == 0) {
    int rg = (ni << 7) + (wn << 6) + (nf << 4) + l15;   // permuted row
    unsigned short* wt = wtailp + (((size_t)(dir << 11) + rg) << 3);
    wt[0] = f2bf(Wih[orig * 4 + 0]);
    wt[1] = f2bf(Wih[orig * 4 + 1]);
    wt[2] = f2bf(Wih[orig * 4 + 2]);
    wt[3] = f2bf(Wih[orig * 4 + 3]);
    wt[4] = f2bf(bih[orig] + bhh[orig]);
    wt[5] = 0; wt[6] = 0; wt[7] = 0;
  }
}

__device__ __forceinline__ void mfma16(const bf16x8 av[4], const bf16x8 bv[4],
                                       f32x4 acc[4][4]) {
#pragma unroll
  for (int mf = 0; mf < 4; ++mf)
#pragma unroll
    for (int nf = 0; nf < 4; ++nf)
      acc[mf][nf] = __builtin_amdgcn_mfma_f32_16x16x32_bf16(av[mf], bv[nf], acc[mf][nf], 0, 0, 0);
}

// ---------------------------------------------------------------------------
// Persistent kernel: 256 blocks x 512 threads (1 block/CU via 128KB LDS),
// cooperative launch => exactly 32 blocks per XCD (pigeonhole at 1/CU).
// Roles: xcc = HW_REG_XCC_ID; rank = per-XCD counter; dir = rank>>4, ni = rank&15.
// The 16 blocks of (xcc,dir) produce/consume one h panel in one physical L2.
// ctrl (uints): [xcc<<5] rank counters; flags at 256 + grp*512 + ni*32
//   (grp = mi*2+dir; per-block single-writer flag, 128B apart).
// ---------------------------------------------------------------------------
__global__ __launch_bounds__(512, 2) void lstm_persist(
    const float* __restrict__ y,
    const unsigned short* __restrict__ Wp,
    const unsigned short* __restrict__ wtailp,
    unsigned short* __restrict__ hf0, unsigned short* __restrict__ hf1,
    unsigned short* __restrict__ hb0, unsigned short* __restrict__ hb1,
    unsigned* __restrict__ ctrl)
{
  __shared__ alignas(16) unsigned short Wl[65536];   // 128 KB W image
  __shared__ unsigned arrive_cnt;
  __shared__ unsigned rank_sh;

  const int tid = threadIdx.x;
  const int w = tid >> 6, lane = tid & 63;

  unsigned xcc;
  asm("s_getreg_b32 %0, hwreg(HW_REG_XCC_ID)" : "=s"(xcc));
  xcc &= 7u;

  if (tid == 0) {
    arrive_cnt = 0u;
    rank_sh = __hip_atomic_fetch_add(ctrl + (xcc << 5), 1u,
                                     __ATOMIC_RELAXED, __HIP_MEMORY_SCOPE_AGENT);
  }
  __syncthreads();
  const int rank = (int)(rank_sh & 31u);
  const int dir = rank >> 4;               // 16 fwd + 16 bwd blocks per XCD
  const int ni  = rank & 15;
  const int mi  = (int)xcc;
  const int bm0 = mi << 8;                 // this XCD's 256 batch rows

  unsigned short* h0 = dir ? hb0 : hf0;
  unsigned short* h1 = dir ? hb1 : hf1;

  const int wm = w >> 1;                   // 0..3: 64-row quarter
  const int wn = w & 1;                    // 0..1: 64-col half
  const int l15 = lane & 15;
  const int lhi = lane >> 4;

  // ---- one-time: copy this block's 128KB W image into LDS (contiguous) ----
  const unsigned short* Wblk = Wp + ((size_t)((dir << 4) | ni) << 16);
#pragma unroll
  for (int i = 0; i < 16; ++i) {
    gl_lds16(Wblk + (size_t)(((i << 9) + tid)) * 8,
             (unsigned short*)Wl + ((i << 12) + (w << 9)));
  }

  // ---- tail B-fragments (wih + bias), register-resident (r8 verbatim) ----
  bf16x8 btail[4];
#pragma unroll
  for (int nf = 0; nf < 4; ++nf) {
    u16x8 wt = *(const u16x8*)(wtailp +
        (((size_t)(dir << 11) + ((ni << 7) | (wn << 6) | (nf << 4) | l15))) * 8);
    u16x8 z = {};
    u16x8 sel = (lhi == 0) ? wt : z;
    btail[nf] = *(bf16x8*)&sel;
  }

  const int j = (((ni << 1) + wn) << 4) + l15;   // hidden index 0..511
  float c_reg[16];
#pragma unroll
  for (int i = 0; i < 16; ++i) c_reg[i] = 0.f;

  const float4* y4 = (const float4*)y;
  unsigned* gflags = ctrl + 256 + (((unsigned)((mi << 1) | dir)) << 9); // 16 flags x 32 u
  unsigned* myflag = gflags + (ni << 5);                               // single writer

  // LDS B-fragment base for this wave (contiguous 1KB per (kt,nf) read)
  const unsigned short* wB = Wl + (wn << 15) + (lane << 3);

  __syncthreads();   // Wl ready (drains global_load_lds)

  const unsigned short* hin = h0;
  unsigned short* hout = h1;

#pragma unroll 1
  for (int t = 0; t < 128; ++t) {
    const int t_eff = dir ? (127 - t) : t;

    // ---- x loads (independent of the flag) ----
    float4 xr[4];
#pragma unroll
    for (int mf = 0; mf < 4; ++mf)
      xr[mf] = y4[(size_t)(bm0 + (wm << 6) + (mf << 4) + l15) * 128 + t_eff];

    // ---- parallel poll: lanes 0-15 of wave0 LOAD all 16 peer flags at once.
    //      Relaxed agent loads: fresh (device-scope bits), and unlike RMWs they
    //      don't lock the flag line -- the publisher's RMW isn't queued behind
    //      poller traffic. (r13's single change vs r11.) ----
    if (t) {
      if (w == 0) {
        const unsigned* fp = gflags + ((lane & 15) << 5);
        while (true) {
          unsigned v = 0;
          if (lane < 16)
            v = __hip_atomic_load(fp, __ATOMIC_RELAXED, __HIP_MEMORY_SCOPE_AGENT);
          bool ok = (lane < 16) ? (v >= (unsigned)t) : true;
          if (__all(ok)) break;
          __builtin_amdgcn_s_sleep(2);
        }
      }
      __syncthreads();
      asm volatile("buffer_inv sc0\n\ts_waitcnt vmcnt(0)" ::: "memory");
    }

    f32x4 acc[4][4];
#pragma unroll
    for (int a = 0; a < 4; ++a)
#pragma unroll
      for (int b = 0; b < 4; ++b) acc[a][b] = (f32x4){0.f, 0.f, 0.f, 0.f};

    if (t) {
      const unsigned short* aBase =
          hin + ((size_t)(bm0 + (wm << 6) + l15) << 9) + (lhi << 3);

      bf16x8 aA[4][4], bT[2][4];

      // slice rotation: block ni starts its k-sweep at slice ni (load-order only)
#define SL(i) ((ni + (i)) & 15)
#define ALOAD(kk, sl)                                                          \
      do {                                                                     \
        const unsigned short* ap_ = aBase + ((kk) << 5);                       \
        aA[sl][0] = *(const bf16x8*)(ap_);                                     \
        aA[sl][1] = *(const bf16x8*)(ap_ + (16 << 9));                         \
        aA[sl][2] = *(const bf16x8*)(ap_ + (32 << 9));                         \
        aA[sl][3] = *(const bf16x8*)(ap_ + (48 << 9));                         \
      } while (0)
#define BLOAD(kk, sl)                                                          \
      do {                                                                     \
        const unsigned short* bp_ = wB + ((kk) << 11);                         \
        bT[sl][0] = *(const bf16x8*)(bp_);                                     \
        bT[sl][1] = *(const bf16x8*)(bp_ + 512);                               \
        bT[sl][2] = *(const bf16x8*)(bp_ + 1024);                              \
        bT[sl][3] = *(const bf16x8*)(bp_ + 1536);                              \
      } while (0)

      // prologue: A slices 0..3 (rotated), B slices 0..1 (rotated)
      ALOAD(SL(0), 0); ALOAD(SL(1), 1); ALOAD(SL(2), 2); ALOAD(SL(3), 3);
      BLOAD(SL(0), 0); BLOAD(SL(1), 1);

      // tail MFMA (x*Wih + bias) FIRST, while prologue loads are in flight
      {
        bf16x8 atail[4];
#pragma unroll
        for (int mf = 0; mf < 4; ++mf) {
          u16x8 at = {};
          if (lhi == 0) {
            at[0] = f2bf(xr[mf].x); at[1] = f2bf(xr[mf].y);
            at[2] = f2bf(xr[mf].z); at[3] = f2bf(xr[mf].w);
            at[4] = 0x3F80;   // 1.0 -> picks up bias row
          }
          atail[mf] = *(bf16x8*)&at;
        }
        mfma16(atail, btail, acc);
      }

#pragma unroll
      for (int i = 0; i < 16; ++i) {
        __builtin_amdgcn_s_setprio(1);
        mfma16(aA[i & 3], bT[i & 1], acc);
        __builtin_amdgcn_s_setprio(0);
        if (i < 12) ALOAD(SL(i + 4), (i + 4) & 3);
        if (i < 14) BLOAD(SL(i + 2), i & 1);
      }
#undef ALOAD
#undef BLOAD
#undef SL
    } else {
      // t=0: h=0, GEMM skipped; just tail
      bf16x8 atail[4];
#pragma unroll
      for (int mf = 0; mf < 4; ++mf) {
        u16x8 at = {};
        if (lhi == 0) {
          at[0] = f2bf(xr[mf].x); at[1] = f2bf(xr[mf].y);
          at[2] = f2bf(xr[mf].z); at[3] = f2bf(xr[mf].w);
          at[4] = 0x3F80;
        }
        atail[mf] = *(bf16x8*)&at;
      }
      mfma16(atail, btail, acc);
    }

    // ---- epilogue: lane-local LSTM cell update, c in registers ----
#pragma unroll
    for (int mf = 0; mf < 4; ++mf) {
#pragma unroll
      for (int r = 0; r < 4; ++r) {
        const float ig = sigm(acc[mf][0][r]);
        const float fg = sigm(acc[mf][1][r]);
        const float gg = tanhfast(acc[mf][2][r]);
        const float og = sigm(acc[mf][3][r]);
        const float cn = fg * c_reg[mf * 4 + r] + ig * gg;
        c_reg[mf * 4 + r] = cn;
        const int b = bm0 + (wm << 6) + (mf << 4) + (lhi << 2) + r;
        hout[((size_t)b << 9) + j] = f2bf(og * tanhfast(cn));
      }
    }

    // ---- publish: per-wave store drain -> LDS arrival -> 8th wave bumps OWN flag ----
    if (t != 127) {
      asm volatile("s_waitcnt vmcnt(0)" ::: "memory");   // own h stores in L2
      if (lane == 0) {
        unsigned old = atomicAdd(&arrive_cnt, 1u);       // intra-block LDS atomic
        if (old == (unsigned)((t << 3) + 7)) {           // last of 8 waves this step
          __hip_atomic_fetch_add(myflag, 1u, __ATOMIC_RELAXED,
                                 __HIP_MEMORY_SCOPE_AGENT);
        }
      }
    }

    const unsigned short* tmp = hin; hin = hout; hout = (unsigned short*)tmp;
  }
}

// ---------------------------------------------------------------------------
// heads: out[b][k] = sigmoid(hf[b]·Wk[0:512] + hb[b]·Wk[512:1024] + bk)
// ---------------------------------------------------------------------------
__global__ __launch_bounds__(256) void heads_k(
    const unsigned short* __restrict__ hf, const unsigned short* __restrict__ hb,
    const float* __restrict__ W1, const float* __restrict__ b1,
    const float* __restrict__ W2, const float* __restrict__ b2,
    const float* __restrict__ W3, const float* __restrict__ b3,
    const float* __restrict__ W4, const float* __restrict__ b4,
    float* __restrict__ out)
{
  const int wid = threadIdx.x >> 6, lane = threadIdx.x & 63;
  const int b = blockIdx.x * 4 + wid;
  const unsigned short* src = (lane < 32) ? (hf + ((size_t)b << 9) + (lane << 4))
                                          : (hb + ((size_t)b << 9) + ((lane - 32) << 4));
  const int woff = lane << 4;
  u16x8 v0 = *(const u16x8*)src;
  u16x8 v1 = *(const u16x8*)(src + 8);
  float hv[16];
#pragma unroll
  for (int e = 0; e < 8; ++e) { hv[e] = bf2f(v0[e]); hv[8 + e] = bf2f(v1[e]); }
  float s0 = 0.f, s1 = 0.f, s2 = 0.f, s3 = 0.f;
#pragma unroll
  for (int e = 0; e < 16; ++e) {
    float h = hv[e];
    s0 += h * W1[woff + e];
    s1 += h * W2[woff + e];
    s2 += h * W3[woff + e];
    s3 += h * W4[woff + e];
  }
#pragma unroll
  for (int off = 32; off >= 1; off >>= 1) {
    s0 += __shfl_xor(s0, off, 64);
    s1 += __shfl_xor(s1, off, 64);
    s2 += __shfl_xor(s2, off, 64);
    s3 += __shfl_xor(s3, off, 64);
  }
  if (lane == 0) {
    out[b * 4 + 0] = sigm(s0 + b1[0]);
    out[b * 4 + 1] = sigm(s1 + b2[0]);
    out[b * 4 + 2] = sigm(s2 + b3[0]);
    out[b * 4 + 3] = sigm(s3 + b4[0]);
  }
}

// ---------------------------------------------------------------------------
extern "C" void kernel_launch(void* const* d_in, const int* in_sizes, int n_in,
                              void* d_out, int out_size, void* d_ws, size_t ws_size,
                              hipStream_t stream) {
  (void)in_sizes; (void)n_in; (void)out_size; (void)ws_size;
  const float* y     = (const float*)d_in[0];
  const float* Wf_ih = (const float*)d_in[1];
  const float* Wf_hh = (const float*)d_in[2];
  const float* bf_ih = (const float*)d_in[3];
  const float* bf_hh = (const float*)d_in[4];
  const float* Wb_ih = (const float*)d_in[5];
  const float* Wb_hh = (const float*)d_in[6];
  const float* bb_ih = (const float*)d_in[7];
  const float* bb_hh = (const float*)d_in[8];
  const float* W1 = (const float*)d_in[9];  const float* b1 = (const float*)d_in[10];
  const float* W2 = (const float*)d_in[11]; const float* b2 = (const float*)d_in[12];
  const float* W3 = (const float*)d_in[13]; const float* b3 = (const float*)d_in[14];
  const float* W4 = (const float*)d_in[15]; const float* b4 = (const float*)d_in[16];

  char* ws = (char*)d_ws;
  const size_t MB = 1ull << 20;
  unsigned short* Wp    = (unsigned short*)(ws);            // 4MB: per-(dir,ni) LDS images
  unsigned short* hf0   = (unsigned short*)(ws + 4 * MB);   // 2MB
  unsigned short* hb0   = (unsigned short*)(ws + 6 * MB);   // 2MB
  unsigned short* hf1   = (unsigned short*)(ws + 8 * MB);   // 2MB
  unsigned short* hb1   = (unsigned short*)(ws + 10 * MB);  // 2MB
  unsigned short* wtail = (unsigned short*)(ws + 12 * MB);  // 64KB
  unsigned* ctrl        = (unsigned*)(ws + 13 * MB);        // rank counters + 256 flags

  hipMemsetAsync(ws + 4 * MB, 0, 4 * MB, stream);    // hf0+hb0 = h(t=0) zeros
  hipMemsetAsync(ws + 13 * MB, 0, 65536, stream);    // ctrl: counters + flags

  prep_k<<<1024, 256, 0, stream>>>(Wf_hh, Wf_ih, bf_ih, bf_hh,
                                   Wb_hh, Wb_ih, bb_ih, bb_hh,
                                   Wp, wtail);

  void* args[] = { (void*)&y, (void*)&Wp, (void*)&wtail,
                   (void*)&hf0, (void*)&hf1, (void*)&hb0, (void*)&hb1, (void*)&ctrl };
  hipLaunchCooperativeKernel((const void*)lstm_persist, dim3(256), dim3(512),
                             args, 0, stream);

  // 128 steps (even): final h is in buffer 0 for both directions
  heads_k<<<512, 256, 0, stream>>>(hf0, hb0, W1, b1, W2, b2, W3, b3, W4, b4,
                                   (float*)d_out);
}